// Round 2
// baseline (441.068 us; speedup 1.0000x reference)
//
#include <hip/hip_runtime.h>

// Nearest-voxel gather: out[i] = f[clip((x[i]+1)/h,0,255) per axis], h=2/255.
// N = 2^24 points, f = 256^3 float32 (67 MB, > L2 32MB, < L3 256MB).
// Memory-bound: 201 MB x-stream + 67 MB out-stream + random gather.

// HIP's float4 is a class type; nontemporal builtins need a clang vector.
typedef float f32x4 __attribute__((ext_vector_type(4)));

__device__ __forceinline__ int vox_idx(float v) {
    // Bit-match the reference: float32 IEEE divide by h (NOT *127.5f —
    // a 1-ulp difference at an integer boundary flips the voxel index).
    const float h = 2.0f / 255.0f;
    float p = (v + 1.0f) / h;
    p = fminf(fmaxf(p, 0.0f), 255.0f);
    return (int)p;  // truncation; p >= 0 so == floor == astype(int32)
}

__global__ __launch_bounds__(256) void voxel_gather_kernel(
    const float* __restrict__ x, const float* __restrict__ f,
    float* __restrict__ out, int n4)
{
    int t = blockIdx.x * blockDim.x + threadIdx.x;
    if (t >= n4) return;

    // 4 points per thread: 12 contiguous floats = three 16B loads.
    const f32x4* x4 = (const f32x4*)x;
    f32x4 a = __builtin_nontemporal_load(&x4[3 * t + 0]);
    f32x4 b = __builtin_nontemporal_load(&x4[3 * t + 1]);
    f32x4 c = __builtin_nontemporal_load(&x4[3 * t + 2]);

    // point k coords: p0=(a0,a1,a2) p1=(a3,b0,b1) p2=(b2,b3,c0) p3=(c1,c2,c3)
    int i0 = (vox_idx(a.x) << 16) | (vox_idx(a.y) << 8) | vox_idx(a.z);
    int i1 = (vox_idx(a.w) << 16) | (vox_idx(b.x) << 8) | vox_idx(b.y);
    int i2 = (vox_idx(b.z) << 16) | (vox_idx(b.w) << 8) | vox_idx(c.x);
    int i3 = (vox_idx(c.y) << 16) | (vox_idx(c.z) << 8) | vox_idx(c.w);

    // Cached gathers — keep f resident in L2/L3 across replays.
    f32x4 o;
    o.x = f[i0];
    o.y = f[i1];
    o.z = f[i2];
    o.w = f[i3];

    __builtin_nontemporal_store(o, &((f32x4*)out)[t]);
}

extern "C" void kernel_launch(void* const* d_in, const int* in_sizes, int n_in,
                              void* d_out, int out_size, void* d_ws, size_t ws_size,
                              hipStream_t stream) {
    const float* x = (const float*)d_in[0];  // (N, 3) float32
    const float* f = (const float*)d_in[1];  // (256,256,256) float32
    float* out = (float*)d_out;              // (N,) float32

    int n = in_sizes[0] / 3;                 // 16777216 points
    int n4 = n / 4;                          // 4 points per thread (n is 2^24)
    dim3 block(256);
    dim3 grid((n4 + block.x - 1) / block.x);
    voxel_gather_kernel<<<grid, block, 0, stream>>>(x, f, out, n4);
}